// Round 1
// baseline (795.013 us; speedup 1.0000x reference)
//
#include <hip/hip_runtime.h>

// z = conv3x3(x, w) (pad 1, cross-correlation, NCHW/OIHW); LIF scan over t:
//   v = v + (z - v)*0.5 ; s = (v >= 1) ; v = s ? 0 : v
// NUMERICS INVARIANT (verified bit-exact R5/R6): per output element the conv
// is a SINGLE sequential f32 FMA chain over k = (tap, ci), tap = ky*3+kx
// outer, ci INNERMOST (Eigen/XLA-CPU order), acc starts at 0; padding taps are
// exact fma no-ops (zero halo). LIF ops separately rounded; *0.5 exact.
// R8: conv -> 512-thread blocks (8 waves), 8x16 tile (180-pos halo, 48.9 KB
// LDS -> 3 blocks/CU = 24 waves/CU vs 20 before); LDS float4-granule XOR
// swizzle kills ds_read_b128 bank aliasing (py vs py+4 rows) and the staging
// lane-map (p3=tid&7, c3=(tid>>3)&7, wave-uniform pos/ci blocks) makes
// ds_write_b32 conflict-free; cib unroll 4 halves lgkm drains. LIF float4.

namespace {
constexpr int T = 16, N = 8, C = 64, H = 64, W = 64;
constexpr int HW   = H * W;       // 4096
constexpr int CHW  = C * HW;      // 262144
constexpr int NCHW = N * CHW;     // 2097152
constexpr int NWT  = C * C * 9;   // 36864
constexpr int PSTR = 68;          // LDS pos-stride in floats (64+4 pad)
constexpr int TH = 8, TW = 16;    // output tile per block
constexpr int PH = TH + 2;        // 10 halo rows
constexpr int PW = TW + 2;        // 18 halo cols
constexpr int NPOS = PH * PW;     // 180 staged positions
}

// Transpose weights (O,I,3,3) -> wt2[tap][ci][cout]: per (tap,ci) couts are
// contiguous -> wave-uniform s_load of 16 floats per wave per (tap,ci).
__global__ void wtr_kernel(const float* __restrict__ w, float* __restrict__ wt2) {
    int i = blockIdx.x * 256 + threadIdx.x;     // i = (cout*64 + ci)*9 + tap
    if (i >= NWT) return;
    int tap  = i % 9;
    int rem  = i / 9;
    int ci   = rem % 64;
    int cout = rem / 64;
    wt2[(tap * 64 + ci) * 64 + cout] = w[i];
}

// Conv only. Block: 512 threads = 8 waves = one (t, n, 8x16 tile), 64 couts.
// Wave w: ph = w&1 picks cols [8ph, 8ph+8); couts [16*(w>>1), +16).
// Lane: px = lane&7 (col), py = lane>>3 (row). Writes z into `zo`.
// LDS element (pos, ci) lives at  pos*PSTR + 4*((ci>>2) ^ ((pos>>3)&7)) + (ci&3)
// -- float4-granule XOR swizzle; reads stay 16B-aligned ds_read_b128.
__global__ __launch_bounds__(512, 6) void conv_kernel(
    const float* __restrict__ x,
    const float* __restrict__ wt2,
    float*       __restrict__ zo)
{
#pragma clang fp contract(off)
    __shared__ float xs[NPOS * PSTR];   // 180*68*4 = 48960 B

    const int tid  = threadIdx.x;
    const int wave = __builtin_amdgcn_readfirstlane(tid >> 6);
    const int lane = tid & 63;
    const int px = lane & 7;
    const int py = lane >> 3;
    const int ph8 = (wave & 1) << 3;   // pixel-half column offset
    const int c0  = (wave >> 1) << 4;  // 16 couts per wave

    const int bid  = blockIdx.x;       // 4096 = 16 t * 8 n * 32 tiles
    const int t    = bid >> 8;
    const int r    = bid & 255;
    const int n    = r >> 5;
    const int tile = r & 31;
    const int th0 = (tile >> 2) << 3;  // 8 tile-rows
    const int tw0 = (tile & 3) << 4;   // 4 tile-cols

    const float* xt = x + (size_t)(t * N + n) * CHW;

    // Stage x[t][n][ci][th0-1..+8][tw0-1..+16] into swizzled LDS (zero halo).
    // j = it*512 + tid sweeps (pb, cb, p3, c3): pos = pb*8+p3 (skip >=180),
    // ci = cb*8+c3. rem = it*8+wave is wave-uniform -> pb, cb scalar.
    const int p3 = tid & 7;
    const int c3 = (tid >> 3) & 7;
#pragma unroll
    for (int it = 0; it < 23; ++it) {
        int rem = it * 8 + wave;        // [0,184)
        int cb  = rem / 23;             // [0,8)
        int pb  = rem - cb * 23;        // [0,23)
        int pos = pb * 8 + p3;
        if (pos < NPOS) {
            int ci = cb * 8 + c3;
            int dy = pos / PW;
            int dx = pos - dy * PW;
            int hh = th0 - 1 + dy;
            int ww = tw0 - 1 + dx;
            float val = 0.0f;
            if ((unsigned)hh < (unsigned)H && (unsigned)ww < (unsigned)W)
                val = xt[ci * HW + hh * W + ww];
            xs[pos * PSTR + ((((ci >> 2) ^ (pb & 7)) << 2) | (ci & 3))] = val;
        }
    }
    __syncthreads();

    float acc[16];
#pragma unroll
    for (int i = 0; i < 16; ++i) acc[i] = 0.0f;

    // Chain per acc[cc]: tap outer (9), ci 0..63 ascending inner; one fmaf
    // per k; only load scheduling varies, never FMA order.
    for (int tap = 0; tap < 9; ++tap) {
        const int ky = tap / 3, kx = tap - 3 * ky;
        const int pos = (py + ky) * PW + (ph8 + px + kx);
        const int g   = (pos >> 3) & 7;                 // read-side swizzle
        const float4* xp = (const float4*)xs + pos * (PSTR / 4);
        const float* wtap = wt2 + tap * 4096 + c0;      // wave-uniform
#pragma unroll 4
        for (int cib = 0; cib < 16; ++cib) {
            const float4 xv = xp[cib ^ g];
            const float* wp = wtap + cib * 256;          // (tap, ci=4*cib) block
#pragma unroll
            for (int cc = 0; cc < 16; ++cc)
                acc[cc] = fmaf(wp[cc], xv.x, acc[cc]);
#pragma unroll
            for (int cc = 0; cc < 16; ++cc)
                acc[cc] = fmaf(wp[64 + cc], xv.y, acc[cc]);
#pragma unroll
            for (int cc = 0; cc < 16; ++cc)
                acc[cc] = fmaf(wp[128 + cc], xv.z, acc[cc]);
#pragma unroll
            for (int cc = 0; cc < 16; ++cc)
                acc[cc] = fmaf(wp[192 + cc], xv.w, acc[cc]);
        }
    }

    float* zt = zo + (size_t)(t * N + n) * CHW;
    const int pbase = (th0 + py) * W + (tw0 + ph8 + px);
#pragma unroll
    for (int cc = 0; cc < 16; ++cc)
        zt[(c0 + cc) * HW + pbase] = acc[cc];
}

// LIF scan, in-place on zo (reads z, writes 0/1 spikes). One thread per FOUR
// consecutive (n,c,h,w) neurons (float4); t-loop carries v in registers.
// Elementwise ops separately rounded, identical per-element order as before
// (*0.5 exact; contraction disabled anyway).
__global__ void lif_kernel(float* __restrict__ zo) {
#pragma clang fp contract(off)
    const int gid = blockIdx.x * 256 + threadIdx.x;   // [0, NCHW/4)
    float4 v;
    v.x = 0.0f; v.y = 0.0f; v.z = 0.0f; v.w = 0.0f;
#pragma unroll
    for (int t = 0; t < T; ++t) {
        float4* p = (float4*)(zo + (size_t)t * NCHW) + gid;
        float4 z = *p;
        float4 s;
#define LIF_STEP(comp) { float d = z.comp - v.comp; float hh = d * 0.5f;      \
        v.comp = v.comp + hh;                                                  \
        if (v.comp >= 1.0f) { s.comp = 1.0f; v.comp = 0.0f; }                  \
        else                { s.comp = 0.0f; } }
        LIF_STEP(x) LIF_STEP(y) LIF_STEP(z) LIF_STEP(w)
#undef LIF_STEP
        *p = s;
    }
}

extern "C" void kernel_launch(void* const* d_in, const int* in_sizes, int n_in,
                              void* d_out, int out_size, void* d_ws, size_t ws_size,
                              hipStream_t stream) {
    const float* x = (const float*)d_in[0];
    const float* w = (const float*)d_in[1];
    if (n_in >= 2 && in_sizes[0] < in_sizes[1]) {   // defensive: pick by size
        const float* tmp = x; x = w; w = tmp;
    }
    float* out = (float*)d_out;
    float* wt2 = (float*)d_ws;                       // 36864 floats = 144 KB

    wtr_kernel<<<(NWT + 255) / 256, 256, 0, stream>>>(w, wt2);
    conv_kernel<<<T * N * 32, 512, 0, stream>>>(x, wt2, out);
    lif_kernel<<<NCHW / 1024, 256, 0, stream>>>(out);
}